// Round 1
// baseline (124.791 us; speedup 1.0000x reference)
//
#include <hip/hip_runtime.h>

// LogSigProdLayer: out[b,j] = (bias[j] + sum_i ls(lx[b,i]*W[i,j])) / 1e4
//   lx = log(relu(x)+1e-3); ls(z) = logsigmoid(z)+ln2 = ln2 - ln(1+e^-z)
// W[i,j]==0 => ls == 0 exactly, so only nonzero weights contribute.
// e^-z = exp2(c_b * w) with c_b = -log2(relu(x)+eps)  (exact algebra).

#define BATCH 8
#define NDIM  4096
#define CHUNK 64     // i-rows per block
#define JT    256    // j-columns per block == blockDim.x

__global__ __launch_bounds__(256) void init_out_kernel(const float* __restrict__ bias,
                                                       float* __restrict__ out) {
    int t = blockIdx.x * 256 + threadIdx.x;     // 0 .. 8*4096-1
    int j = t & (NDIM - 1);
    out[t] = bias[j] * 1e-4f;
}

__global__ __launch_bounds__(256) void logsig_main_kernel(const float* __restrict__ x,
                                                          const float* __restrict__ w,
                                                          float* __restrict__ out) {
    __shared__ float c[BATCH * CHUNK];          // c[b][ii] = -log2(relu(x)+eps), 2 KB

    const int tid = threadIdx.x;
    const int i0  = blockIdx.y * CHUNK;

    // Stage per-chunk transformed activations into LDS (512 values, 2 per thread).
    for (int t = tid; t < BATCH * CHUNK; t += 256) {
        int b  = t >> 6;          // t / CHUNK
        int ii = t & (CHUNK - 1); // t % CHUNK
        float xv = x[b * NDIM + i0 + ii];
        c[t] = -__builtin_amdgcn_logf(fmaxf(xv, 0.0f) + 1e-3f);  // v_log_f32 = log2
    }
    __syncthreads();

    const int j = blockIdx.x * JT + tid;
    const float* wp = w + (size_t)i0 * NDIM + j;

    float acc[BATCH];
    #pragma unroll
    for (int b = 0; b < BATCH; ++b) acc[b] = 0.0f;
    int cnt = 0;

    #pragma unroll 4
    for (int ii = 0; ii < CHUNK; ++ii) {
        float wv = wp[(size_t)ii * NDIM];       // coalesced: lanes are consecutive j
        if (wv != 0.0f) {                       // all-zero wave => s_cbranch_execz skip
            cnt++;
            #pragma unroll
            for (int b = 0; b < BATCH; ++b) {
                // e^-z = exp2(c*w); acc += log2(1 + e^-z)
                float e = __builtin_amdgcn_exp2f(c[b * CHUNK + ii] * wv);
                acc[b] += __builtin_amdgcn_logf(1.0f + e);
            }
        }
    }

    // sum_i ls = ln2 * (cnt - acc_b); final scale 1e-4
    const float s = 0.69314718056f * 1e-4f;
    float fcnt = (float)cnt;
    #pragma unroll
    for (int b = 0; b < BATCH; ++b) {
        atomicAdd(&out[b * NDIM + j], (fcnt - acc[b]) * s);
    }
}

extern "C" void kernel_launch(void* const* d_in, const int* in_sizes, int n_in,
                              void* d_out, int out_size, void* d_ws, size_t ws_size,
                              hipStream_t stream) {
    const float* x    = (const float*)d_in[0];   // [8, 4096]
    const float* wgt  = (const float*)d_in[1];   // [4096, 4096]
    const float* bias = (const float*)d_in[2];   // [4096]
    float* out = (float*)d_out;                  // [8, 4096]

    // out is re-poisoned before every timed launch: initialize with bias term.
    init_out_kernel<<<(BATCH * NDIM) / 256, 256, 0, stream>>>(bias, out);

    dim3 grid(NDIM / JT, NDIM / CHUNK);          // (16 j-tiles, 64 i-chunks) = 1024 blocks
    logsig_main_kernel<<<grid, 256, 0, stream>>>(x, wgt, out);
}